// Round 14
// baseline (288.100 us; speedup 1.0000x reference)
//
#include <hip/hip_runtime.h>
#include <stdint.h>

namespace {

typedef _Float16 f16x8 __attribute__((ext_vector_type(8)));
typedef float f32x16 __attribute__((ext_vector_type(16)));

__device__ __forceinline__ uint32_t pkrtz(float a, float b) {
  return __builtin_bit_cast(uint32_t, __builtin_amdgcn_cvt_pkrtz(a, b));
}

constexpr int IMG = 512, K = 51;
constexpr int NT = 512;     // 8 waves: (group g) x (row parity) x (i-half)
constexpr int XB = 64;      // pixels per block
constexpr int YB = 8;       // output rows per block
constexpr int NSS = YB / 2; // 4 supersteps
constexpr int FROWS = 59;   // static rows y0-25 .. y0+33 (no ring)
constexpr int FG = 15;      // 16B granules per channel-row = 120 f16 cols
constexpr int HP = 26;      // u32 pitch of H pair-table per x
constexpr int NQ = 6;       // K=16 chunks

constexpr int GR_B  = FROWS * 16;        // 944 B per granule
constexpr int CH_B  = FG * GR_B;         // 14160 B per channel
constexpr int FR_U32 = 3 * FG * FROWS;   // frame tile granule-quads (*4 u32)
constexpr int H_U32  = 2 * 64 * HP;      // 13312 B
constexpr int VL_U16 = 2 * 52 * 64;      // 13312 B  (V table, f16)
constexpr int EX_F32 = 4 * 2 * 2 * 2 * 3 * 32;  // 12288 B
constexpr int NVT = 2 * 51 * 32;         // 3264 V pair-tasks per stage
// LDS: 42480 + 13312 + 13312 + 12288 = 81392 B -> 2 blocks/CU, 16 waves/CU

__device__ __forceinline__ int exidx(int s, int ih, int g, int yp, int c, int n) {
  return ((((s * 2 + ih) * 2 + g) * 2 + yp) * 3 + c) * 32 + n;
}

__global__ __launch_bounds__(NT, 4)
void sepconv(const float* __restrict__ fr0, const float* __restrict__ fr2,
             const float* __restrict__ V1, const float* __restrict__ H1,
             const float* __restrict__ V2, const float* __restrict__ H2,
             float* __restrict__ out)
{
  __shared__ __align__(16) uint32_t fr32[FR_U32 * 4];
  __shared__ uint32_t hL[H_U32];
  __shared__ _Float16 vL[VL_U16];
  __shared__ float exL[EX_F32];
  uint32_t* vL32 = (uint32_t*)vL;

  const int tid = threadIdx.x;
  const int l    = tid & 63;
  const int w    = tid >> 6;
  const int g    = w & 1;          // 32-px group
  const int ypar = (w >> 1) & 1;   // row parity
  const int ih   = w >> 2;         // i-half: 0 -> taps 0..18, 1 -> taps 19..50
  const int n    = l & 31;         // pixel in group
  const int kb   = l >> 5;         // k-half
  const int x0   = blockIdx.x * XB;
  const int y0   = blockIdx.y * YB;
  const int b    = blockIdx.z;
  const size_t plane = (size_t)IMG * IMG;   // 2^18
  const int xloc = 32 * g + n;

  // H staging role: 2 rows x 4 segments x 64 px = 512 threads exactly
  const int hx = tid & 63, hseg = (tid >> 6) & 3, hyy = tid >> 8;
  const int segp0 = (hseg == 0) ? 0 : (hseg == 1) ? 7 : (hseg == 2) ? 13 : 20;
  const int segn  = (hseg & 1) ? 6 : 7;

  #pragma unroll 1
  for (int f = 0; f < 2; ++f) {
    const float* __restrict__ Vf = (f ? V2 : V1) + (size_t)b * K * plane;
    const float* __restrict__ Hf = (f ? H2 : H1) + (size_t)b * K * plane;
    const float* __restrict__ frb = (f ? fr2 : fr0) + (size_t)b * 3 * plane;

    float ha[7], hb[7];          // H carries (next superstep)
    float vca[7], vcb[7];        // V carries (next superstep)

    auto loadVC = [&](int yb) {  // V rows yb, yb+1 -> vca/vcb
      #pragma unroll
      for (int k = 0; k < 7; ++k) {
        int t = tid + NT * k;
        if (t < NVT) {
          int rowp = (t >= NVT / 2);
          int rem = t - rowp * (NVT / 2);
          int tap = rem >> 5, pxp = rem & 31;
          const float* vp = Vf + ((size_t)tap << 18)
                            + (size_t)(yb + rowp) * IMG + x0 + 2 * pxp;
          vca[k] = vp[0]; vcb[k] = vp[1];
        }
      }
    };
    auto writeVC = [&]() {
      #pragma unroll
      for (int k = 0; k < 7; ++k) {
        int t = tid + NT * k;
        if (t < NVT) {
          int rowp = (t >= NVT / 2);
          int rem = t - rowp * (NVT / 2);
          int tap = rem >> 5, pxp = rem & 31;
          vL32[(rowp * 52 + tap) * 32 + pxp] = pkrtz(vca[k], vcb[k]);
        }
      }
    };

    __syncthreads();   // previous pass's LDS reads (incl. final phase) done

    // ---- prologue: H rows y0,y0+1 + V rows y0,y0+1 (loads issued first) ----
    float pha[7], phb[7];
    {
      const int yH = y0 + hyy;
      #pragma unroll
      for (int m = 0; m < 7; ++m)
        if (m < segn) {
          int p = segp0 + m, j0 = 2 * p;
          pha[m] = Hf[((size_t)j0 << 18) + (size_t)yH * IMG + x0 + hx];
          phb[m] = (j0 + 1 <= 50)
                 ? Hf[((size_t)(j0 + 1) << 18) + (size_t)yH * IMG + x0 + hx]
                 : 0.f;
        }
    }
    loadVC(y0);
    // ---- prologue: frame rows y0-25..y0+33 (10620 pair-tasks, 3 passes) ----
    #pragma unroll 1
    for (int pass = 0; pass < 3; ++pass) {
      float ta[7], tb[7];
      #pragma unroll
      for (int k2 = 0; k2 < 7; ++k2) {
        int task = tid + NT * (pass * 7 + k2);
        if (task < 10620) {
          int rr = task / 180; int rem = task - rr * 180;
          int c = rem / 60, pc = rem - c * 60;
          int row = min(max(y0 - 25 + rr, 0), IMG - 1);
          int ca = min(max(x0 - 25 + 2 * pc, 0), IMG - 1);
          int cb = min(max(x0 - 25 + 2 * pc + 1, 0), IMG - 1);
          const float* rp = frb + (size_t)c * plane + (size_t)row * IMG;
          ta[k2] = rp[ca]; tb[k2] = rp[cb];
        }
      }
      if (pass == 0) {       // H-table writes under pass-0 loads
        #pragma unroll
        for (int m = 0; m < 7; ++m)
          if (m < segn)
            hL[(hyy * 64 + hx) * HP + segp0 + m] = pkrtz(pha[m], phb[m]);
      }
      if (pass == 1) writeVC();   // V-table writes under pass-1 loads
      #pragma unroll
      for (int k2 = 0; k2 < 7; ++k2) {
        int task = tid + NT * (pass * 7 + k2);
        if (task < 10620) {
          int rr = task / 180; int rem = task - rr * 180;
          int c = rem / 60, pc = rem - c * 60;
          fr32[((c * FG + (pc >> 2)) * FROWS + rr) * 4 + (pc & 3)] =
              pkrtz(ta[k2], tb[k2]);
        }
      }
    }
    __syncthreads();

    #pragma unroll 1
    for (int s = 0; s < NSS; ++s) {
      const int y = y0 + 2 * s;
      if (s > 0) {
        __syncthreads();   // previous superstep's hL/vL reads complete
        #pragma unroll
        for (int m = 0; m < 7; ++m)
          if (m < segn)
            hL[(hyy * 64 + hx) * HP + segp0 + m] = pkrtz(ha[m], hb[m]);
        writeVC();
        __syncthreads();   // tables visible
      }

      // ---- A base (static slot, no ring) ----
      const int lr = (ih ? 19 : 0) + 2 * s + ypar + n;   // local row
      const char* pA = (const char*)fr32 + (4 * g + kb) * GR_B + lr * 16;
      const uint32_t* hrow = hL + (ypar * 64 + xloc) * HP;
      // g=1,kb=1,q=5 would read granule 15 (not staged); B there is all-zero
      // (taps j>=57) -> redirect to a staged granule: finite * 0 = 0.
      const bool q5fix = (g & kb) != 0;

      // ---- MFMA cluster: q-outer (runtime -> bq not hoistable), c-inner ----
      f32x16 D0, D1, D2;
      #pragma unroll
      for (int e = 0; e < 16; ++e) { D0[e] = 0.f; D1[e] = 0.f; D2[e] = 0.f; }

      __builtin_amdgcn_s_setprio(1);
      #pragma unroll 1
      for (int q = 0; q < NQ; ++q) {
        uint4 bq;
        {
          int j0 = 16 * q + 8 * kb - n;
          int pb = j0 >> 1;
          uint32_t rd[5];
          #pragma unroll
          for (int ww = 0; ww < 5; ++ww) {
            int pw = pb + ww;
            bool ok = (unsigned)pw <= 25u;
            uint32_t vr = hrow[ok ? pw : 0];
            rd[ww] = ok ? vr : 0u;
          }
          uint32_t fv[4];
          #pragma unroll
          for (int v2 = 0; v2 < 4; ++v2) {
            uint32_t al =
                (uint32_t)((((uint64_t)rd[v2 + 1] << 32) | rd[v2]) >> 16);
            fv[v2] = (n & 1) ? al : rd[v2];
          }
          bq = make_uint4(fv[0], fv[1], fv[2], fv[3]);
        }
        int aoff = q * (2 * GR_B);
        if (q == 5 && q5fix) aoff -= 2 * GR_B;
        const char* pAq = pA + aoff;
        const f16x8 A0 = *(const f16x8*)(pAq);
        D0 = __builtin_amdgcn_mfma_f32_32x32x16_f16(
                 A0, __builtin_bit_cast(f16x8, bq), D0, 0, 0, 0);
        const f16x8 A1 = *(const f16x8*)(pAq + CH_B);
        D1 = __builtin_amdgcn_mfma_f32_32x32x16_f16(
                 A1, __builtin_bit_cast(f16x8, bq), D1, 0, 0, 0);
        const f16x8 A2 = *(const f16x8*)(pAq + 2 * CH_B);
        D2 = __builtin_amdgcn_mfma_f32_32x32x16_f16(
                 A2, __builtin_bit_cast(f16x8, bq), D2, 0, 0, 0);
      }
      __builtin_amdgcn_s_setprio(0);

      // ---- carry loads for s+1 (consumed at next barrier-pair) ----
      if (s + 1 < NSS) {
        const int yH = y + 2 + hyy;
        #pragma unroll
        for (int m = 0; m < 7; ++m)
          if (m < segn) {
            int p = segp0 + m, j0 = 2 * p;
            ha[m] = Hf[((size_t)j0 << 18) + (size_t)yH * IMG + x0 + hx];
            hb[m] = (j0 + 1 <= 50)
                  ? Hf[((size_t)(j0 + 1) << 18) + (size_t)yH * IMG + x0 + hx]
                  : 0.f;
          }
        loadVC(y + 2);
      }

      // ---- epilogue: V (from LDS) weighted reduce of D, cross-kb fold ----
      const _Float16* vr0 = vL + (ypar * 52) * 64 + xloc;
      float a0 = 0.f, a1 = 0.f, a2 = 0.f;
      if (ih) {
        const _Float16* vrb = vr0 + 19 * 64 + kb * 256;
        #pragma unroll
        for (int r = 0; r < 16; ++r) {
          float vt = (float)vrb[((r & 3) + 8 * (r >> 2)) * 64];
          a0 += vt * D0[r]; a1 += vt * D1[r]; a2 += vt * D2[r];
        }
      } else {
        const _Float16* vrb = vr0 + kb * 256;
        #pragma unroll
        for (int r = 0; r < 8; ++r) {
          float vt = (float)vrb[((r & 3) + 8 * (r >> 2)) * 64];
          a0 += vt * D0[r]; a1 += vt * D1[r]; a2 += vt * D2[r];
        }
        #pragma unroll
        for (int e = 0; e < 3; ++e) {
          float vt = (kb == 0) ? (float)vr0[(16 + e) * 64] : 0.f;
          a0 += vt * D0[8 + e]; a1 += vt * D1[8 + e]; a2 += vt * D2[8 + e];
        }
      }
      a0 += __shfl_xor(a0, 32, 64);
      a1 += __shfl_xor(a1, 32, 64);
      a2 += __shfl_xor(a2, 32, 64);

      // ---- partials: f=0 writes, f=1 accumulates ----
      if (l < 32) {
        if (f == 0) {
          exL[exidx(s, ih, g, ypar, 0, l)] = a0;
          exL[exidx(s, ih, g, ypar, 1, l)] = a1;
          exL[exidx(s, ih, g, ypar, 2, l)] = a2;
        } else {
          exL[exidx(s, ih, g, ypar, 0, l)] += a0;
          exL[exidx(s, ih, g, ypar, 1, l)] += a1;
          exL[exidx(s, ih, g, ypar, 2, l)] += a2;
        }
      }
    }
  }

  // ---- final phase: reduce ih-halves, coalesced store (no out read) ----
  __syncthreads();
  #pragma unroll
  for (int t = 0; t < 3; ++t) {
    int oi = tid + NT * t;          // 1536 outputs
    int px = oi & 63, rem = oi >> 6;
    int c = rem % 3, r = rem / 3;
    int ss = r >> 1, yp = r & 1, gg = px >> 5, nn = px & 31;
    float val = exL[exidx(ss, 0, gg, yp, c, nn)]
              + exL[exidx(ss, 1, gg, yp, c, nn)];
    size_t oidx = ((size_t)(b * 3 + c) * IMG + y0 + r) * IMG + x0 + px;
    out[oidx] = val;
  }
}

} // namespace

extern "C" void kernel_launch(void* const* d_in, const int* in_sizes, int n_in,
                              void* d_out, int out_size, void* d_ws, size_t ws_size,
                              hipStream_t stream)
{
  const float* frame0 = (const float*)d_in[0];
  const float* frame2 = (const float*)d_in[1];
  const float* V1 = (const float*)d_in[2];
  const float* H1 = (const float*)d_in[3];
  const float* V2 = (const float*)d_in[4];
  const float* H2 = (const float*)d_in[5];
  float* o = (float*)d_out;

  dim3 grid(IMG / XB, IMG / YB, 2);
  dim3 block(NT);
  hipLaunchKernelGGL(sepconv, grid, block, 0, stream,
                     frame0, frame2, V1, H1, V2, H2, o);
}